// Round 12
// baseline (200.441 us; speedup 1.0000x reference)
//
#include <hip/hip_runtime.h>
#include <hip/hip_bf16.h>

#define NN 8192
#define CC 256
#define CQK 32
#define JS 4   // pass1 j-splits

using bf16x8 = __attribute__((ext_vector_type(8))) short;
using s16x4  = __attribute__((ext_vector_type(4))) short;
using f32x4  = __attribute__((ext_vector_type(4))) float;
using f32x16 = __attribute__((ext_vector_type(16))) float;

static __device__ __forceinline__ unsigned short f2bf(float x) {
    union { __hip_bfloat16 h; unsigned short u; } cv;
    cv.h = __float2bfloat16(x);
    return cv.u;
}
static __device__ __forceinline__ float bf2f(unsigned short u) {
    union { unsigned short u; __hip_bfloat16 h; } cv;
    cv.u = u;
    return __bfloat162float(cv.h);
}
static __device__ __forceinline__ float fexp2(float x) { return __builtin_amdgcn_exp2f(x); }
// pack two f32 -> packed bf16 dword. VERIFIED path only (r10 lesson).
static __device__ __forceinline__ int packbf(float lo, float hi) {
    return (int)f2bf(lo) | ((int)f2bf(hi) << 16);
}

// ---------------------------------------------------------------------------
// Kernel 0: Wv f32 -> bf16 once.
// ---------------------------------------------------------------------------
__global__ __launch_bounds__(256) void conv_w_kernel(
    const float* __restrict__ Wv, unsigned short* __restrict__ WvB)
{
    const int idx = (blockIdx.x * 256 + threadIdx.x) * 4;   // 64 blocks
    float4 v = *(const float4*)(Wv + idx);
    s16x4 pk;
    pk[0] = (short)f2bf(v.x); pk[1] = (short)f2bf(v.y);
    pk[2] = (short)f2bf(v.z); pk[3] = (short)f2bf(v.w);
    *(s16x4*)(WvB + idx) = pk;
}

// ---------------------------------------------------------------------------
// Kernel 1a: q = (f @ Wqk^T) * sqrt(log2 e), stored hi/lo bf16.
// ---------------------------------------------------------------------------
__global__ __launch_bounds__(256) void proj_q_kernel(
    const float* __restrict__ f, const float* __restrict__ Wqk,
    unsigned short* __restrict__ qhi, unsigned short* __restrict__ qlo)
{
    __shared__ __align__(16) float fl[8][CC];
    const int t  = threadIdx.x;
    const int r0 = blockIdx.x * 8;
    {
        const float4* src = (const float4*)(f + (size_t)r0 * CC);
        float4* dst = (float4*)&fl[0][0];
        dst[t]       = src[t];
        dst[t + 256] = src[t + 256];
    }
    __syncthreads();
    const int cq = t & 31;
    const int rg = t >> 5;
    const float4* w4 = (const float4*)(Wqk + (size_t)cq * CC);
    float a = 0.f;
    for (int k4 = 0; k4 < 64; ++k4) {
        float4 wq = w4[k4];
        const float4 fv = *(const float4*)&fl[rg][k4 * 4];
        a = fmaf(wq.x, fv.x, a);
        a = fmaf(wq.y, fv.y, a);
        a = fmaf(wq.z, fv.z, a);
        a = fmaf(wq.w, fv.w, a);
    }
    a *= 1.2011224087864498f;              // sqrt(log2 e) -> exp2 domain
    unsigned short hh = f2bf(a);
    unsigned short ll = f2bf(a - bf2f(hh));
    qhi[(size_t)(r0 + rg) * CQK + cq] = hh;
    qlo[(size_t)(r0 + rg) * CQK + cq] = ll;
}

// ---------------------------------------------------------------------------
// Kernel 1b: v = f @ Wv^T + bv via bf16 32x32x16 MFMA; Wv pre-converted bf16.
// Output layout vB[i>>3][c][i&7] bf16 -> PV B-frags are coalesced b128 loads.
// ---------------------------------------------------------------------------
__global__ __launch_bounds__(256, 4) void proj_v_kernel(
    const float* __restrict__ f, const unsigned short* __restrict__ WvB,
    const float* __restrict__ bv, unsigned short* __restrict__ vB)
{
    const int t    = threadIdx.x;
    const int lane = t & 63;
    const int w    = t >> 6;
    const int l31  = lane & 31;
    const int h    = lane >> 5;
    const int nb   = blockIdx.x * 32;
    const int cb   = w * 64;

    f32x16 acc[2];
#pragma unroll
    for (int cf = 0; cf < 2; ++cf)
#pragma unroll
        for (int r = 0; r < 16; ++r) acc[cf][r] = 0.f;

    const float* frow = f + (size_t)(nb + l31) * CC;
#pragma unroll
    for (int ks = 0; ks < 16; ++ks) {
        const int k0 = ks * 16 + 8 * h;
        float4 a0 = *(const float4*)(frow + k0);
        float4 a1 = *(const float4*)(frow + k0 + 4);
        bf16x8 af;
        af[0] = (short)f2bf(a0.x); af[1] = (short)f2bf(a0.y);
        af[2] = (short)f2bf(a0.z); af[3] = (short)f2bf(a0.w);
        af[4] = (short)f2bf(a1.x); af[5] = (short)f2bf(a1.y);
        af[6] = (short)f2bf(a1.z); af[7] = (short)f2bf(a1.w);
#pragma unroll
        for (int cf = 0; cf < 2; ++cf) {
            const bf16x8 bw = *(const bf16x8*)(WvB + (size_t)(cb + 32 * cf + l31) * CC + k0);
            acc[cf] = __builtin_amdgcn_mfma_f32_32x32x16_bf16(af, bw, acc[cf], 0, 0, 0);
        }
    }
#pragma unroll
    for (int cf = 0; cf < 2; ++cf) {
        const int cg = cb + 32 * cf + l31;
        const float bvc = bv[cg];
#pragma unroll
        for (int rg = 0; rg < 4; ++rg) {
            const int ib = (nb >> 3) + rg;
            s16x4 pk;
#pragma unroll
            for (int r = 0; r < 4; ++r)
                pk[r] = (short)f2bf(acc[cf][4 * rg + r] + bvc);
            *(s16x4*)(vB + ((size_t)ib * CC + cg) * 8 + 4 * h) = pk;
        }
    }
}

// ---------------------------------------------------------------------------
// Kernel 2: per-i partial denominators over a j-range (no max tracking;
// exp2-domain energies bounded, f32-safe).
// ---------------------------------------------------------------------------
#define P1BODY(C0, C1, C2, C3, N0, N1, N2, N3, NJ)                             \
    {                                                                          \
        const size_t qnr = (size_t)((NJ) + l31) * CQK;                         \
        N0 = *(const bf16x8*)(qhi + qnr + 8 * h);                              \
        N1 = *(const bf16x8*)(qhi + qnr + 16 + 8 * h);                         \
        N2 = *(const bf16x8*)(qlo + qnr + 8 * h);                              \
        N3 = *(const bf16x8*)(qlo + qnr + 16 + 8 * h);                         \
        f32x16 e0 = {0,0,0,0,0,0,0,0,0,0,0,0,0,0,0,0};                         \
        f32x16 e1 = {0,0,0,0,0,0,0,0,0,0,0,0,0,0,0,0};                         \
        e0 = __builtin_amdgcn_mfma_f32_32x32x16_bf16(C2, bih0, e0, 0, 0, 0);   \
        e1 = __builtin_amdgcn_mfma_f32_32x32x16_bf16(C3, bih1, e1, 0, 0, 0);   \
        e0 = __builtin_amdgcn_mfma_f32_32x32x16_bf16(C0, bil0, e0, 0, 0, 0);   \
        e1 = __builtin_amdgcn_mfma_f32_32x32x16_bf16(C1, bil1, e1, 0, 0, 0);   \
        e0 = __builtin_amdgcn_mfma_f32_32x32x16_bf16(C0, bih0, e0, 0, 0, 0);   \
        e1 = __builtin_amdgcn_mfma_f32_32x32x16_bf16(C1, bih1, e1, 0, 0, 0);   \
        f32x16 ee = e0 + e1;                                                   \
        float a_ = 0.f;                                                        \
        _Pragma("unroll")                                                      \
        for (int r = 0; r < 16; ++r) a_ += fexp2(ee[r]);                       \
        s += a_;                                                               \
    }

__global__ __launch_bounds__(256, 4) void pass1_kernel(
    const unsigned short* __restrict__ qhi,
    const unsigned short* __restrict__ qlo,
    float* __restrict__ ps)
{
    const int t    = threadIdx.x;
    const int lane = t & 63;
    const int w    = t >> 6;
    const int l31  = lane & 31;
    const int h    = lane >> 5;
    const int i0   = (blockIdx.x & 255) * 32;
    const int js   = blockIdx.x >> 8;
    const int JCH  = NN / JS / 4;            // 512 j per wave
    const int jbase = js * (NN / JS) + w * JCH;

    const size_t qir = (size_t)(i0 + l31) * CQK;
    const bf16x8 bih0 = *(const bf16x8*)(qhi + qir + 8 * h);
    const bf16x8 bih1 = *(const bf16x8*)(qhi + qir + 16 + 8 * h);
    const bf16x8 bil0 = *(const bf16x8*)(qlo + qir + 8 * h);
    const bf16x8 bil1 = *(const bf16x8*)(qlo + qir + 16 + 8 * h);

    float s = 0.f;

    bf16x8 qa0, qa1, qa2, qa3, qb0, qb1, qb2, qb3;
    {
        const size_t q0 = (size_t)(jbase + l31) * CQK;
        qa0 = *(const bf16x8*)(qhi + q0 + 8 * h);
        qa1 = *(const bf16x8*)(qhi + q0 + 16 + 8 * h);
        qa2 = *(const bf16x8*)(qlo + q0 + 8 * h);
        qa3 = *(const bf16x8*)(qlo + q0 + 16 + 8 * h);
    }
    for (int st = 0; st < JCH; st += 64) {
        P1BODY(qa0, qa1, qa2, qa3, qb0, qb1, qb2, qb3, jbase + st + 32)
        const int nx = (st + 64 < JCH) ? jbase + st + 64 : jbase + st;
        P1BODY(qb0, qb1, qb2, qb3, qa0, qa1, qa2, qa3, nx)
    }
    s += __shfl_xor(s, 32);      // merge the two h-halves (same i-col)

    __shared__ float rs[4][32];
    if (lane < 32) rs[w][l31] = s;
    __syncthreads();
    if (t < 32) {
        float sf = rs[0][t] + rs[1][t] + rs[2][t] + rs[3][t];
        ps[(size_t)js * NN + i0 + t] = sf;
    }
}

// ---------------------------------------------------------------------------
// Kernel 2b: merge j-split partial sums; bias[i] = log2(sum).
// ---------------------------------------------------------------------------
__global__ __launch_bounds__(256) void finalize_kernel(
    const float* __restrict__ ps, float* __restrict__ bias)
{
    int i = blockIdx.x * 256 + threadIdx.x;
    float s = ps[i];
#pragma unroll
    for (int k = 1; k < JS; ++k) s += ps[(size_t)k * NN + i];
    bias[i] = __builtin_amdgcn_logf(s);   // v_log_f32 = log2
}

// ---------------------------------------------------------------------------
// Kernel 3: barrier-free PV, LEAN 4-wave/SIMD variant.
// Key change vs r5-r11: wave c-extent halved to 64 -> acc = 2 x f32x16 =
// 32 AGPR; total live ~120 unified fits the 128-reg bucket -> 4 waves/SIMD
// (m69 pow2 buckets; 152 regs was pinning us at 2). NO manual pipelining:
// with 4 waves, TLP hides the E-chain + FINISH latency (r7/r9: in-wave
// pipelining is compiler-redundant anyway). #pragma unroll 1 pins pressure.
// Cost: E redundancy R=4 (MFMA x1.43, FINISH x2) -- paid for by 2x waves.
// Block: 4 waves = 2jw x 2cw = 64j x 128c. Grid: 128 jblk x 2 cblk x ISPLIT.
// ---------------------------------------------------------------------------
template<int ISPLIT, bool DIRECT>
__global__ __launch_bounds__(256, 4) void pass2_kernel(
    const unsigned short* __restrict__ qhi,
    const unsigned short* __restrict__ qlo,
    const unsigned short* __restrict__ vB,
    const float* __restrict__ bias,
    const float* __restrict__ f,
    const float* __restrict__ gp,
    float* __restrict__ dst)
{
    const int t    = threadIdx.x;
    const int lane = t & 63;
    const int w    = t >> 6;
    const int l31  = lane & 31;
    const int h    = lane >> 5;

    int slot, isp;
    if (ISPLIT == 4) {
        // XCD-aware: each XCD pair owns one isp -> its vB/q slices stay in L2
        const int bid = blockIdx.x;
        isp  = (bid & 7) >> 1;
        slot = ((bid >> 3) << 1) | (bid & 1);   // 0..255, bijective
    } else {
        isp  = blockIdx.x % ISPLIT;
        slot = blockIdx.x / ISPLIT;             // 0..255
    }
    const int jblk = slot >> 1;                 // 0..127
    const int cblk = slot & 1;                  // 0..1
    const int jrow = jblk * 64 + 32 * (w & 1);
    const int cb   = cblk * 128 + 64 * (w >> 1);
    const int IL   = NN / ISPLIT;
    const int ibase = isp * IL;
    const int iend  = ibase + IL;

    const size_t qjr = (size_t)(jrow + l31) * CQK;
    const bf16x8 bjh0 = *(const bf16x8*)(qhi + qjr + 8 * h);
    const bf16x8 bjh1 = *(const bf16x8*)(qhi + qjr + 16 + 8 * h);
    const bf16x8 bjl0 = *(const bf16x8*)(qlo + qjr + 8 * h);
    const bf16x8 bjl1 = *(const bf16x8*)(qlo + qjr + 16 + 8 * h);

    f32x16 acc0, acc1;
#pragma unroll
    for (int r = 0; r < 16; ++r) { acc0[r] = 0.f; acc1[r] = 0.f; }

#pragma unroll 1
    for (int i0s = ibase; i0s < iend; i0s += 32) {
        // q_i A-frags
        const size_t qir = (size_t)(i0s + l31) * CQK;
        const bf16x8 aih0 = *(const bf16x8*)(qhi + qir + 8 * h);
        const bf16x8 aih1 = *(const bf16x8*)(qhi + qir + 16 + 8 * h);
        const bf16x8 ail0 = *(const bf16x8*)(qlo + qir + 8 * h);
        const bf16x8 ail1 = *(const bf16x8*)(qlo + qir + 16 + 8 * h);

        // V B-frags: [s2][cf], 64 c per wave
        bf16x8 vf00 = *(const bf16x8*)(vB + ((size_t)((i0s >> 3) + 0 + h) * CC + cb + l31) * 8);
        bf16x8 vf01 = *(const bf16x8*)(vB + ((size_t)((i0s >> 3) + 0 + h) * CC + cb + 32 + l31) * 8);
        bf16x8 vf10 = *(const bf16x8*)(vB + ((size_t)((i0s >> 3) + 2 + h) * CC + cb + l31) * 8);
        bf16x8 vf11 = *(const bf16x8*)(vB + ((size_t)((i0s >> 3) + 2 + h) * CC + cb + 32 + l31) * 8);

        // bias for rows i = i0s + 4h + r + 8rg
        f32x4 b40 = *(const f32x4*)(bias + i0s + 0  + 4 * h);
        f32x4 b41 = *(const f32x4*)(bias + i0s + 8  + 4 * h);
        f32x4 b42 = *(const f32x4*)(bias + i0s + 16 + 4 * h);
        f32x4 b43 = *(const f32x4*)(bias + i0s + 24 + 4 * h);

        // E tile: single 6-MFMA accumulate chain (latency hidden by TLP)
        f32x16 ee = {0,0,0,0,0,0,0,0,0,0,0,0,0,0,0,0};
        ee = __builtin_amdgcn_mfma_f32_32x32x16_bf16(ail1, bjh1, ee, 0, 0, 0);
        ee = __builtin_amdgcn_mfma_f32_32x32x16_bf16(ail0, bjh0, ee, 0, 0, 0);
        ee = __builtin_amdgcn_mfma_f32_32x32x16_bf16(aih1, bjl1, ee, 0, 0, 0);
        ee = __builtin_amdgcn_mfma_f32_32x32x16_bf16(aih0, bjl0, ee, 0, 0, 0);
        ee = __builtin_amdgcn_mfma_f32_32x32x16_bf16(aih1, bjh1, ee, 0, 0, 0);
        ee = __builtin_amdgcn_mfma_f32_32x32x16_bf16(aih0, bjh0, ee, 0, 0, 0);

        // p = exp2(e - bias_i), pack -> dwords (round-3-verified path)
        int d0[4], d1[4];
        d0[0] = packbf(fexp2(ee[0]  - b40[0]), fexp2(ee[1]  - b40[1]));
        d1[0] = packbf(fexp2(ee[2]  - b40[2]), fexp2(ee[3]  - b40[3]));
        d0[1] = packbf(fexp2(ee[4]  - b41[0]), fexp2(ee[5]  - b41[1]));
        d1[1] = packbf(fexp2(ee[6]  - b41[2]), fexp2(ee[7]  - b41[3]));
        d0[2] = packbf(fexp2(ee[8]  - b42[0]), fexp2(ee[9]  - b42[1]));
        d1[2] = packbf(fexp2(ee[10] - b42[2]), fexp2(ee[11] - b42[3]));
        d0[3] = packbf(fexp2(ee[12] - b43[0]), fexp2(ee[13] - b43[1]));
        d1[3] = packbf(fexp2(ee[14] - b43[2]), fexp2(ee[15] - b43[3]));

        // redistribute (verified shfl_xor(32)+select) and PV
#pragma unroll
        for (int s2 = 0; s2 < 2; ++s2) {
            const int a_ = d0[2 * s2], b_ = d0[2 * s2 + 1];
            const int c_ = d1[2 * s2], d_ = d1[2 * s2 + 1];
            const int pa = __shfl_xor(a_, 32);
            const int pb = __shfl_xor(b_, 32);
            const int pc = __shfl_xor(c_, 32);
            const int pd = __shfl_xor(d_, 32);
            union { int i[4]; bf16x8 v; } pf;
            pf.i[0] = h ? pb : a_;
            pf.i[1] = h ? pd : c_;
            pf.i[2] = h ? b_ : pa;
            pf.i[3] = h ? d_ : pc;
            acc0 = __builtin_amdgcn_mfma_f32_32x32x16_bf16(pf.v, s2 ? vf10 : vf00, acc0, 0, 0, 0);
            acc1 = __builtin_amdgcn_mfma_f32_32x32x16_bf16(pf.v, s2 ? vf11 : vf01, acc1, 0, 0, 0);
        }
    }

    if (DIRECT) {
        const float g = gp[0];
#pragma unroll
        for (int cf = 0; cf < 2; ++cf) {
            const int c = cb + 32 * cf + l31;
            const f32x16& a = cf ? acc1 : acc0;
#pragma unroll
            for (int rg = 0; rg < 4; ++rg)
#pragma unroll
                for (int r = 0; r < 4; ++r) {
                    const int j = jrow + 4 * h + r + 8 * rg;
                    dst[(size_t)j * CC + c] = fmaf(g, a[4 * rg + r], f[(size_t)j * CC + c]);
                }
        }
    } else {
        float* part = dst + (size_t)isp * NN * CC;
#pragma unroll
        for (int cf = 0; cf < 2; ++cf) {
            const int c = cb + 32 * cf + l31;
            const f32x16& a = cf ? acc1 : acc0;
#pragma unroll
            for (int rg = 0; rg < 4; ++rg)
#pragma unroll
                for (int r = 0; r < 4; ++r) {
                    const int j = jrow + 4 * h + r + 8 * rg;
                    part[(size_t)j * CC + c] = a[4 * rg + r];
                }
        }
    }
}

// ---------------------------------------------------------------------------
// Kernel 4: out = gamma * sum_splits(part) + f
// ---------------------------------------------------------------------------
template<int SPLIT>
__global__ __launch_bounds__(256) void reduce_kernel(
    const float* __restrict__ part, const float* __restrict__ f,
    const float* __restrict__ gp, float* __restrict__ out)
{
    size_t idx = (size_t)blockIdx.x * 256 + threadIdx.x;   // f32x4 units
    const f32x4* p4 = (const f32x4*)part;
    f32x4 s = p4[idx];
#pragma unroll
    for (int k = 1; k < SPLIT; ++k) s += p4[(size_t)k * (NN * CC / 4) + idx];
    f32x4 fv = ((const f32x4*)f)[idx];
    float g = gp[0];
    f32x4 o;
#pragma unroll
    for (int r = 0; r < 4; ++r) o[r] = fmaf(g, s[r], fv[r]);
    ((f32x4*)out)[idx] = o;
}

// ---------------------------------------------------------------------------
extern "C" void kernel_launch(void* const* d_in, const int* in_sizes, int n_in,
                              void* d_out, int out_size, void* d_ws, size_t ws_size,
                              hipStream_t stream) {
    const float* f     = (const float*)d_in[0];
    const float* Wqk   = (const float*)d_in[1];
    const float* Wv    = (const float*)d_in[2];
    const float* bv    = (const float*)d_in[3];
    const float* gamma = (const float*)d_in[4];
    float* out = (float*)d_out;

    char* ws = (char*)d_ws;
    unsigned short* qhi = (unsigned short*)ws;                         // 512 KB
    unsigned short* qlo = (unsigned short*)(ws + (512 << 10));         // 512 KB
    unsigned short* vB  = (unsigned short*)(ws + (1 << 20));           // 4 MB
    float* ps   = (float*)(ws + (5 << 20));                            // 128 KB
    float* bias = (float*)(ws + (5 << 20) + (256 << 10));              // 32 KB
    unsigned short* WvB = (unsigned short*)(ws + (5 << 20) + (512 << 10)); // 128 KB
    float* part = (float*)(ws + (6 << 20));                            // ISPLIT*8 MB

    conv_w_kernel<<<dim3(CC * CC / 1024), dim3(256), 0, stream>>>(Wv, WvB);
    proj_q_kernel<<<dim3(NN / 8), dim3(256), 0, stream>>>(f, Wqk, qhi, qlo);
    proj_v_kernel<<<dim3(NN / 32), dim3(256), 0, stream>>>(f, WvB, bv, vB);
    pass1_kernel<<<dim3((NN / 32) * JS), dim3(256), 0, stream>>>(qhi, qlo, ps);
    finalize_kernel<<<dim3(NN / 256), dim3(256), 0, stream>>>(ps, bias);

    const size_t PB = (size_t)NN * CC * 4;   // one partial buffer: 8 MB
    const size_t B0 = (size_t)6 << 20;
    if (ws_size >= B0 + 4 * PB) {
        pass2_kernel<4, false><<<dim3(256 * 4), dim3(256), 0, stream>>>(qhi, qlo, vB, bias, f, gamma, part);
        reduce_kernel<4><<<dim3(NN * CC / 1024), dim3(256), 0, stream>>>(part, f, gamma, out);
    } else if (ws_size >= B0 + 2 * PB) {
        pass2_kernel<2, false><<<dim3(256 * 2), dim3(256), 0, stream>>>(qhi, qlo, vB, bias, f, gamma, part);
        reduce_kernel<2><<<dim3(NN * CC / 1024), dim3(256), 0, stream>>>(part, f, gamma, out);
    } else if (ws_size >= B0 + 1 * PB) {
        pass2_kernel<1, false><<<dim3(256), dim3(256), 0, stream>>>(qhi, qlo, vB, bias, f, gamma, part);
        reduce_kernel<1><<<dim3(NN * CC / 1024), dim3(256), 0, stream>>>(part, f, gamma, out);
    } else {
        pass2_kernel<1, true><<<dim3(256), dim3(256), 0, stream>>>(qhi, qlo, vB, bias, f, gamma, out);
    }
}

// Round 13
// 184.622 us; speedup vs baseline: 1.0857x; 1.0857x over previous
//
#include <hip/hip_runtime.h>
#include <hip/hip_bf16.h>

#define NN 8192
#define CC 256
#define CQK 32
#define JS 4   // pass1 j-splits

using bf16x8 = __attribute__((ext_vector_type(8))) short;
using s16x4  = __attribute__((ext_vector_type(4))) short;
using f32x4  = __attribute__((ext_vector_type(4))) float;
using f32x16 = __attribute__((ext_vector_type(16))) float;

static __device__ __forceinline__ unsigned short f2bf(float x) {
    union { __hip_bfloat16 h; unsigned short u; } cv;
    cv.h = __float2bfloat16(x);
    return cv.u;
}
static __device__ __forceinline__ float bf2f(unsigned short u) {
    union { unsigned short u; __hip_bfloat16 h; } cv;
    cv.u = u;
    return __bfloat162float(cv.h);
}
static __device__ __forceinline__ float fexp2(float x) { return __builtin_amdgcn_exp2f(x); }
// pack two f32 -> packed bf16 dword. VERIFIED path only (r10 lesson:
// v_cvt_pk_bf16_f32 inline asm broke correctness on this toolchain).
static __device__ __forceinline__ int packbf(float lo, float hi) {
    return (int)f2bf(lo) | ((int)f2bf(hi) << 16);
}

// ---------------------------------------------------------------------------
// Kernel 0: Wv f32 -> bf16 once.
// ---------------------------------------------------------------------------
__global__ __launch_bounds__(256) void conv_w_kernel(
    const float* __restrict__ Wv, unsigned short* __restrict__ WvB)
{
    const int idx = (blockIdx.x * 256 + threadIdx.x) * 4;   // 64 blocks
    float4 v = *(const float4*)(Wv + idx);
    s16x4 pk;
    pk[0] = (short)f2bf(v.x); pk[1] = (short)f2bf(v.y);
    pk[2] = (short)f2bf(v.z); pk[3] = (short)f2bf(v.w);
    *(s16x4*)(WvB + idx) = pk;
}

// ---------------------------------------------------------------------------
// Kernel 1a: q = (f @ Wqk^T) * sqrt(log2 e), stored hi/lo bf16.
// ---------------------------------------------------------------------------
__global__ __launch_bounds__(256) void proj_q_kernel(
    const float* __restrict__ f, const float* __restrict__ Wqk,
    unsigned short* __restrict__ qhi, unsigned short* __restrict__ qlo)
{
    __shared__ __align__(16) float fl[8][CC];
    const int t  = threadIdx.x;
    const int r0 = blockIdx.x * 8;
    {
        const float4* src = (const float4*)(f + (size_t)r0 * CC);
        float4* dst = (float4*)&fl[0][0];
        dst[t]       = src[t];
        dst[t + 256] = src[t + 256];
    }
    __syncthreads();
    const int cq = t & 31;
    const int rg = t >> 5;
    const float4* w4 = (const float4*)(Wqk + (size_t)cq * CC);
    float a = 0.f;
    for (int k4 = 0; k4 < 64; ++k4) {
        float4 wq = w4[k4];
        const float4 fv = *(const float4*)&fl[rg][k4 * 4];
        a = fmaf(wq.x, fv.x, a);
        a = fmaf(wq.y, fv.y, a);
        a = fmaf(wq.z, fv.z, a);
        a = fmaf(wq.w, fv.w, a);
    }
    a *= 1.2011224087864498f;              // sqrt(log2 e) -> exp2 domain
    unsigned short hh = f2bf(a);
    unsigned short ll = f2bf(a - bf2f(hh));
    qhi[(size_t)(r0 + rg) * CQK + cq] = hh;
    qlo[(size_t)(r0 + rg) * CQK + cq] = ll;
}

// ---------------------------------------------------------------------------
// Kernel 1b: v = f @ Wv^T + bv via bf16 32x32x16 MFMA; Wv pre-converted bf16.
// Output layout vB[i>>3][c][i&7] bf16 -> PV B-frags are coalesced b128 loads.
// ---------------------------------------------------------------------------
__global__ __launch_bounds__(256, 4) void proj_v_kernel(
    const float* __restrict__ f, const unsigned short* __restrict__ WvB,
    const float* __restrict__ bv, unsigned short* __restrict__ vB)
{
    const int t    = threadIdx.x;
    const int lane = t & 63;
    const int w    = t >> 6;
    const int l31  = lane & 31;
    const int h    = lane >> 5;
    const int nb   = blockIdx.x * 32;
    const int cb   = w * 64;

    f32x16 acc[2];
#pragma unroll
    for (int cf = 0; cf < 2; ++cf)
#pragma unroll
        for (int r = 0; r < 16; ++r) acc[cf][r] = 0.f;

    const float* frow = f + (size_t)(nb + l31) * CC;
#pragma unroll
    for (int ks = 0; ks < 16; ++ks) {
        const int k0 = ks * 16 + 8 * h;
        float4 a0 = *(const float4*)(frow + k0);
        float4 a1 = *(const float4*)(frow + k0 + 4);
        bf16x8 af;
        af[0] = (short)f2bf(a0.x); af[1] = (short)f2bf(a0.y);
        af[2] = (short)f2bf(a0.z); af[3] = (short)f2bf(a0.w);
        af[4] = (short)f2bf(a1.x); af[5] = (short)f2bf(a1.y);
        af[6] = (short)f2bf(a1.z); af[7] = (short)f2bf(a1.w);
#pragma unroll
        for (int cf = 0; cf < 2; ++cf) {
            const bf16x8 bw = *(const bf16x8*)(WvB + (size_t)(cb + 32 * cf + l31) * CC + k0);
            acc[cf] = __builtin_amdgcn_mfma_f32_32x32x16_bf16(af, bw, acc[cf], 0, 0, 0);
        }
    }
#pragma unroll
    for (int cf = 0; cf < 2; ++cf) {
        const int cg = cb + 32 * cf + l31;
        const float bvc = bv[cg];
#pragma unroll
        for (int rg = 0; rg < 4; ++rg) {
            const int ib = (nb >> 3) + rg;
            s16x4 pk;
#pragma unroll
            for (int r = 0; r < 4; ++r)
                pk[r] = (short)f2bf(acc[cf][4 * rg + r] + bvc);
            *(s16x4*)(vB + ((size_t)ib * CC + cg) * 8 + 4 * h) = pk;
        }
    }
}

// ---------------------------------------------------------------------------
// Kernel 2: per-i partial denominators over a j-range (no max tracking;
// exp2-domain energies bounded, f32-safe).
// ---------------------------------------------------------------------------
#define P1BODY(C0, C1, C2, C3, N0, N1, N2, N3, NJ)                             \
    {                                                                          \
        const size_t qnr = (size_t)((NJ) + l31) * CQK;                         \
        N0 = *(const bf16x8*)(qhi + qnr + 8 * h);                              \
        N1 = *(const bf16x8*)(qhi + qnr + 16 + 8 * h);                         \
        N2 = *(const bf16x8*)(qlo + qnr + 8 * h);                              \
        N3 = *(const bf16x8*)(qlo + qnr + 16 + 8 * h);                         \
        f32x16 e0 = {0,0,0,0,0,0,0,0,0,0,0,0,0,0,0,0};                         \
        f32x16 e1 = {0,0,0,0,0,0,0,0,0,0,0,0,0,0,0,0};                         \
        e0 = __builtin_amdgcn_mfma_f32_32x32x16_bf16(C2, bih0, e0, 0, 0, 0);   \
        e1 = __builtin_amdgcn_mfma_f32_32x32x16_bf16(C3, bih1, e1, 0, 0, 0);   \
        e0 = __builtin_amdgcn_mfma_f32_32x32x16_bf16(C0, bil0, e0, 0, 0, 0);   \
        e1 = __builtin_amdgcn_mfma_f32_32x32x16_bf16(C1, bil1, e1, 0, 0, 0);   \
        e0 = __builtin_amdgcn_mfma_f32_32x32x16_bf16(C0, bih0, e0, 0, 0, 0);   \
        e1 = __builtin_amdgcn_mfma_f32_32x32x16_bf16(C1, bih1, e1, 0, 0, 0);   \
        f32x16 ee = e0 + e1;                                                   \
        float a_ = 0.f;                                                        \
        _Pragma("unroll")                                                      \
        for (int r = 0; r < 16; ++r) a_ += fexp2(ee[r]);                       \
        s += a_;                                                               \
    }

__global__ __launch_bounds__(256, 4) void pass1_kernel(
    const unsigned short* __restrict__ qhi,
    const unsigned short* __restrict__ qlo,
    float* __restrict__ ps)
{
    const int t    = threadIdx.x;
    const int lane = t & 63;
    const int w    = t >> 6;
    const int l31  = lane & 31;
    const int h    = lane >> 5;
    const int i0   = (blockIdx.x & 255) * 32;
    const int js   = blockIdx.x >> 8;
    const int JCH  = NN / JS / 4;            // 512 j per wave
    const int jbase = js * (NN / JS) + w * JCH;

    const size_t qir = (size_t)(i0 + l31) * CQK;
    const bf16x8 bih0 = *(const bf16x8*)(qhi + qir + 8 * h);
    const bf16x8 bih1 = *(const bf16x8*)(qhi + qir + 16 + 8 * h);
    const bf16x8 bil0 = *(const bf16x8*)(qlo + qir + 8 * h);
    const bf16x8 bil1 = *(const bf16x8*)(qlo + qir + 16 + 8 * h);

    float s = 0.f;

    bf16x8 qa0, qa1, qa2, qa3, qb0, qb1, qb2, qb3;
    {
        const size_t q0 = (size_t)(jbase + l31) * CQK;
        qa0 = *(const bf16x8*)(qhi + q0 + 8 * h);
        qa1 = *(const bf16x8*)(qhi + q0 + 16 + 8 * h);
        qa2 = *(const bf16x8*)(qlo + q0 + 8 * h);
        qa3 = *(const bf16x8*)(qlo + q0 + 16 + 8 * h);
    }
    for (int st = 0; st < JCH; st += 64) {
        P1BODY(qa0, qa1, qa2, qa3, qb0, qb1, qb2, qb3, jbase + st + 32)
        const int nx = (st + 64 < JCH) ? jbase + st + 64 : jbase + st;
        P1BODY(qb0, qb1, qb2, qb3, qa0, qa1, qa2, qa3, nx)
    }
    s += __shfl_xor(s, 32);      // merge the two h-halves (same i-col)

    __shared__ float rs[4][32];
    if (lane < 32) rs[w][l31] = s;
    __syncthreads();
    if (t < 32) {
        float sf = rs[0][t] + rs[1][t] + rs[2][t] + rs[3][t];
        ps[(size_t)js * NN + i0 + t] = sf;
    }
}

// ---------------------------------------------------------------------------
// Kernel 2b: merge j-split partial sums; bias[i] = log2(sum).
// ---------------------------------------------------------------------------
__global__ __launch_bounds__(256) void finalize_kernel(
    const float* __restrict__ ps, float* __restrict__ bias)
{
    int i = blockIdx.x * 256 + threadIdx.x;
    float s = ps[i];
#pragma unroll
    for (int k = 1; k < JS; ++k) s += ps[(size_t)k * NN + i];
    bias[i] = __builtin_amdgcn_logf(s);   // v_log_f32 = log2
}

// ---------------------------------------------------------------------------
// Kernel 3: PV with LDS P-exchange (R=1 softmax work).
// Block: 4 waves (jw = w&1 j-half, cw = w>>1 c-half), 64j x 256c, i-step 64.
// Per macro-step each wave computes ONE E tile (i = i0s + 32*cw) -> exp2/pack
// (r3-verified math) -> 4x ds_write_b64 into padded P tile [32][20 dwords]
// -> ONE __syncthreads -> all waves b128-read PV A-frags for BOTH i-subtiles.
// Slot math: ee[4rg+r] is row i = 8rg+4h+r; d0/d1[rg] = i-pairs (4rg+2h,
// 4rg+2h+1) -> b64 at slot 4rg+2h; PV A-frag (k = 16*s2 + 8h..8h+7) =
// b128 at slot 8*s2+4h. Double-buffered P => 1 barrier per 64-i (safe:
// iter m+2's writes to buf follow barrier(m+1) which follows all buf-reads).
// vs r11: MFMA/wave/64i 28->22, softmax VALU halved, 16 bpermute+selects ->
// 4 write + 4 read. __launch_bounds__(256,2): no register cap (r6 lesson).
// ---------------------------------------------------------------------------
template<int ISPLIT, bool DIRECT>
__global__ __launch_bounds__(256, 2) void pass2_kernel(
    const unsigned short* __restrict__ qhi,
    const unsigned short* __restrict__ qlo,
    const unsigned short* __restrict__ vB,
    const float* __restrict__ bias,
    const float* __restrict__ f,
    const float* __restrict__ gp,
    float* __restrict__ dst)
{
    __shared__ __align__(16) int plds[2][2][2][32][20];   // [buf][jw][it][j][slot]
    const int t    = threadIdx.x;
    const int lane = t & 63;
    const int w    = t >> 6;
    const int l31  = lane & 31;
    const int h    = lane >> 5;
    const int jw   = w & 1;
    const int cw   = w >> 1;

    int jblk, isp;
    if (ISPLIT == 4) {
        // XCD-aware: each XCD pair owns one isp -> its vB/q slices stay in L2
        const int bid = blockIdx.x;
        isp  = (bid & 7) >> 1;
        jblk = ((bid >> 3) << 1) | (bid & 1);   // 0..127, bijective
    } else if (ISPLIT == 2) {
        isp  = blockIdx.x & 1;
        jblk = blockIdx.x >> 1;
    } else {
        isp  = 0;
        jblk = blockIdx.x;
    }
    const int jb   = jblk * 64;
    const int jrow = jb + 32 * jw;
    const int cb   = 128 * cw;
    const int IL   = NN / ISPLIT;
    const int ibase = isp * IL;
    const int iend  = ibase + IL;

    const size_t qjr = (size_t)(jrow + l31) * CQK;
    const bf16x8 bjh0 = *(const bf16x8*)(qhi + qjr + 8 * h);
    const bf16x8 bjh1 = *(const bf16x8*)(qhi + qjr + 16 + 8 * h);
    const bf16x8 bjl0 = *(const bf16x8*)(qlo + qjr + 8 * h);
    const bf16x8 bjl1 = *(const bf16x8*)(qlo + qjr + 16 + 8 * h);

    f32x16 acc[4];
#pragma unroll
    for (int cf = 0; cf < 4; ++cf)
#pragma unroll
        for (int r = 0; r < 16; ++r) acc[cf][r] = 0.f;

    int buf = 0;
#pragma unroll 1
    for (int i0s = ibase; i0s < iend; i0s += 64) {
        const int ie = i0s + 32 * cw;         // this wave's E tile
        const size_t qir = (size_t)(ie + l31) * CQK;
        const bf16x8 aih0 = *(const bf16x8*)(qhi + qir + 8 * h);
        const bf16x8 aih1 = *(const bf16x8*)(qhi + qir + 16 + 8 * h);
        const bf16x8 ail0 = *(const bf16x8*)(qlo + qir + 8 * h);
        const bf16x8 ail1 = *(const bf16x8*)(qlo + qir + 16 + 8 * h);
        const f32x4 b40 = *(const f32x4*)(bias + ie + 0  + 4 * h);
        const f32x4 b41 = *(const f32x4*)(bias + ie + 8  + 4 * h);
        const f32x4 b42 = *(const f32x4*)(bias + ie + 16 + 4 * h);
        const f32x4 b43 = *(const f32x4*)(bias + ie + 24 + 4 * h);

        // E tile: single 6-MFMA accumulate chain
        f32x16 ee = {0,0,0,0,0,0,0,0,0,0,0,0,0,0,0,0};
        ee = __builtin_amdgcn_mfma_f32_32x32x16_bf16(ail1, bjh1, ee, 0, 0, 0);
        ee = __builtin_amdgcn_mfma_f32_32x32x16_bf16(ail0, bjh0, ee, 0, 0, 0);
        ee = __builtin_amdgcn_mfma_f32_32x32x16_bf16(aih1, bjl1, ee, 0, 0, 0);
        ee = __builtin_amdgcn_mfma_f32_32x32x16_bf16(aih0, bjl0, ee, 0, 0, 0);
        ee = __builtin_amdgcn_mfma_f32_32x32x16_bf16(aih1, bjh1, ee, 0, 0, 0);
        ee = __builtin_amdgcn_mfma_f32_32x32x16_bf16(aih0, bjh0, ee, 0, 0, 0);

        // p = exp2(e - bias_i), packed i-pairs (verified path)
        int d0[4], d1[4];
        d0[0] = packbf(fexp2(ee[0]  - b40[0]), fexp2(ee[1]  - b40[1]));
        d1[0] = packbf(fexp2(ee[2]  - b40[2]), fexp2(ee[3]  - b40[3]));
        d0[1] = packbf(fexp2(ee[4]  - b41[0]), fexp2(ee[5]  - b41[1]));
        d1[1] = packbf(fexp2(ee[6]  - b41[2]), fexp2(ee[7]  - b41[3]));
        d0[2] = packbf(fexp2(ee[8]  - b42[0]), fexp2(ee[9]  - b42[1]));
        d1[2] = packbf(fexp2(ee[10] - b42[2]), fexp2(ee[11] - b42[3]));
        d0[3] = packbf(fexp2(ee[12] - b43[0]), fexp2(ee[13] - b43[1]));
        d1[3] = packbf(fexp2(ee[14] - b43[2]), fexp2(ee[15] - b43[3]));

        // write P tile: slots (4rg+2h, 4rg+2h+1); h halves interleave, no overlap
#pragma unroll
        for (int rg = 0; rg < 4; ++rg) {
            int2 pr; pr.x = d0[rg]; pr.y = d1[rg];
            *(int2*)&plds[buf][jw][cw][l31][4 * rg + 2 * h] = pr;
        }
        __syncthreads();

        // PV: both i-subtiles, A-frags straight from LDS
#pragma unroll
        for (int it = 0; it < 2; ++it) {
            const int ig = i0s + 32 * it;
#pragma unroll
            for (int s2 = 0; s2 < 2; ++s2) {
                const bf16x8 pf = *(const bf16x8*)&plds[buf][jw][it][l31][8 * s2 + 4 * h];
                const size_t vbase = ((size_t)((ig >> 3) + 2 * s2 + h) * CC + cb + l31) * 8;
#pragma unroll
                for (int cf = 0; cf < 4; ++cf) {
                    const bf16x8 vf = *(const bf16x8*)(vB + vbase + (size_t)cf * 256);
                    acc[cf] = __builtin_amdgcn_mfma_f32_32x32x16_bf16(pf, vf, acc[cf], 0, 0, 0);
                }
            }
        }
        buf ^= 1;
    }

    if (DIRECT) {
        const float g = gp[0];
#pragma unroll
        for (int cf = 0; cf < 4; ++cf) {
            const int c = cb + 32 * cf + l31;
#pragma unroll
            for (int rg = 0; rg < 4; ++rg)
#pragma unroll
                for (int r = 0; r < 4; ++r) {
                    const int j = jrow + 4 * h + r + 8 * rg;
                    dst[(size_t)j * CC + c] =
                        fmaf(g, acc[cf][4 * rg + r], f[(size_t)j * CC + c]);
                }
        }
    } else {
        float* part = dst + (size_t)isp * NN * CC;
#pragma unroll
        for (int cf = 0; cf < 4; ++cf) {
            const int c = cb + 32 * cf + l31;
#pragma unroll
            for (int rg = 0; rg < 4; ++rg)
#pragma unroll
                for (int r = 0; r < 4; ++r) {
                    const int j = jrow + 4 * h + r + 8 * rg;
                    part[(size_t)j * CC + c] = acc[cf][4 * rg + r];
                }
        }
    }
}

// ---------------------------------------------------------------------------
// Kernel 4: out = gamma * sum_splits(part) + f
// ---------------------------------------------------------------------------
template<int SPLIT>
__global__ __launch_bounds__(256) void reduce_kernel(
    const float* __restrict__ part, const float* __restrict__ f,
    const float* __restrict__ gp, float* __restrict__ out)
{
    size_t idx = (size_t)blockIdx.x * 256 + threadIdx.x;   // f32x4 units
    const f32x4* p4 = (const f32x4*)part;
    f32x4 s = p4[idx];
#pragma unroll
    for (int k = 1; k < SPLIT; ++k) s += p4[(size_t)k * (NN * CC / 4) + idx];
    f32x4 fv = ((const f32x4*)f)[idx];
    float g = gp[0];
    f32x4 o;
#pragma unroll
    for (int r = 0; r < 4; ++r) o[r] = fmaf(g, s[r], fv[r]);
    ((f32x4*)out)[idx] = o;
}

// ---------------------------------------------------------------------------
extern "C" void kernel_launch(void* const* d_in, const int* in_sizes, int n_in,
                              void* d_out, int out_size, void* d_ws, size_t ws_size,
                              hipStream_t stream) {
    const float* f     = (const float*)d_in[0];
    const float* Wqk   = (const float*)d_in[1];
    const float* Wv    = (const float*)d_in[2];
    const float* bv    = (const float*)d_in[3];
    const float* gamma = (const float*)d_in[4];
    float* out = (float*)d_out;

    char* ws = (char*)d_ws;
    unsigned short* qhi = (unsigned short*)ws;                         // 512 KB
    unsigned short* qlo = (unsigned short*)(ws + (512 << 10));         // 512 KB
    unsigned short* vB  = (unsigned short*)(ws + (1 << 20));           // 4 MB
    float* ps   = (float*)(ws + (5 << 20));                            // 128 KB
    float* bias = (float*)(ws + (5 << 20) + (256 << 10));              // 32 KB
    unsigned short* WvB = (unsigned short*)(ws + (5 << 20) + (512 << 10)); // 128 KB
    float* part = (float*)(ws + (6 << 20));                            // ISPLIT*8 MB

    conv_w_kernel<<<dim3(CC * CC / 1024), dim3(256), 0, stream>>>(Wv, WvB);
    proj_q_kernel<<<dim3(NN / 8), dim3(256), 0, stream>>>(f, Wqk, qhi, qlo);
    proj_v_kernel<<<dim3(NN / 32), dim3(256), 0, stream>>>(f, WvB, bv, vB);
    pass1_kernel<<<dim3((NN / 32) * JS), dim3(256), 0, stream>>>(qhi, qlo, ps);
    finalize_kernel<<<dim3(NN / 256), dim3(256), 0, stream>>>(ps, bias);

    const size_t PB = (size_t)NN * CC * 4;   // one partial buffer: 8 MB
    const size_t B0 = (size_t)6 << 20;
    if (ws_size >= B0 + 4 * PB) {
        pass2_kernel<4, false><<<dim3(128 * 4), dim3(256), 0, stream>>>(qhi, qlo, vB, bias, f, gamma, part);
        reduce_kernel<4><<<dim3(NN * CC / 1024), dim3(256), 0, stream>>>(part, f, gamma, out);
    } else if (ws_size >= B0 + 2 * PB) {
        pass2_kernel<2, false><<<dim3(128 * 2), dim3(256), 0, stream>>>(qhi, qlo, vB, bias, f, gamma, part);
        reduce_kernel<2><<<dim3(NN * CC / 1024), dim3(256), 0, stream>>>(part, f, gamma, out);
    } else if (ws_size >= B0 + 1 * PB) {
        pass2_kernel<1, false><<<dim3(128), dim3(256), 0, stream>>>(qhi, qlo, vB, bias, f, gamma, part);
        reduce_kernel<1><<<dim3(NN * CC / 1024), dim3(256), 0, stream>>>(part, f, gamma, out);
    } else {
        pass2_kernel<1, true><<<dim3(128), dim3(256), 0, stream>>>(qhi, qlo, vB, bias, f, gamma, out);
    }
}

// Round 14
// 163.332 us; speedup vs baseline: 1.2272x; 1.1303x over previous
//
#include <hip/hip_runtime.h>
#include <hip/hip_bf16.h>

#define NN 8192
#define CC 256
#define CQK 32
#define JS 4   // pass1 j-splits

using bf16x8 = __attribute__((ext_vector_type(8))) short;
using f16x8  = __attribute__((ext_vector_type(8))) _Float16;
using s16x4  = __attribute__((ext_vector_type(4))) short;
using f32x4  = __attribute__((ext_vector_type(4))) float;
using f32x16 = __attribute__((ext_vector_type(16))) float;

static __device__ __forceinline__ unsigned short f2bf(float x) {
    union { __hip_bfloat16 h; unsigned short u; } cv;
    cv.h = __float2bfloat16(x);
    return cv.u;
}
static __device__ __forceinline__ float fexp2(float x) { return __builtin_amdgcn_exp2f(x); }
// pack two positive f32 -> packed bf16 dword by TRUNCATION (p > 0 always;
// 2 insts vs ~9 for RNE; bf16-truncate rel err 2^-8 on P, fine vs threshold).
static __device__ __forceinline__ int packbf(float lo, float hi) {
    union { float f; unsigned u; } a, b;
    a.f = lo; b.f = hi;
    return (int)((b.u & 0xFFFF0000u) | (a.u >> 16));
}

// ---------------------------------------------------------------------------
// Kernel 0: Wv f32 -> bf16 once.
// ---------------------------------------------------------------------------
__global__ __launch_bounds__(256) void conv_w_kernel(
    const float* __restrict__ Wv, unsigned short* __restrict__ WvB)
{
    const int idx = (blockIdx.x * 256 + threadIdx.x) * 4;   // 64 blocks
    float4 v = *(const float4*)(Wv + idx);
    s16x4 pk;
    pk[0] = (short)f2bf(v.x); pk[1] = (short)f2bf(v.y);
    pk[2] = (short)f2bf(v.z); pk[3] = (short)f2bf(v.w);
    *(s16x4*)(WvB + idx) = pk;
}

// ---------------------------------------------------------------------------
// Kernel 1a: q = (f @ Wqk^T) * sqrt(log2 e), stored as SINGLE f16.
// f16's 11 mantissa bits give |de| <~ 2^-10 * e on energies -> ~2-3% on the
// dominant softmax weight, same order as bf16-P error. Replaces bf16 hi/lo
// (E: 6 MFMAs -> 2).
// ---------------------------------------------------------------------------
__global__ __launch_bounds__(256) void proj_q_kernel(
    const float* __restrict__ f, const float* __restrict__ Wqk,
    unsigned short* __restrict__ qf)
{
    __shared__ __align__(16) float fl[8][CC];
    const int t  = threadIdx.x;
    const int r0 = blockIdx.x * 8;
    {
        const float4* src = (const float4*)(f + (size_t)r0 * CC);
        float4* dst = (float4*)&fl[0][0];
        dst[t]       = src[t];
        dst[t + 256] = src[t + 256];
    }
    __syncthreads();
    const int cq = t & 31;
    const int rg = t >> 5;
    const float4* w4 = (const float4*)(Wqk + (size_t)cq * CC);
    float a = 0.f;
    for (int k4 = 0; k4 < 64; ++k4) {
        float4 wq = w4[k4];
        const float4 fv = *(const float4*)&fl[rg][k4 * 4];
        a = fmaf(wq.x, fv.x, a);
        a = fmaf(wq.y, fv.y, a);
        a = fmaf(wq.z, fv.z, a);
        a = fmaf(wq.w, fv.w, a);
    }
    a *= 1.2011224087864498f;              // sqrt(log2 e) -> exp2 domain
    union { _Float16 h; unsigned short u; } cv;
    cv.h = (_Float16)a;                    // RNE
    qf[(size_t)(r0 + rg) * CQK + cq] = cv.u;
}

// ---------------------------------------------------------------------------
// Kernel 1b: v = f @ Wv^T + bv via bf16 32x32x16 MFMA; Wv pre-converted bf16.
// Output layout vB[i>>3][c][i&7] bf16 -> PV B-frags are coalesced b128 loads.
// ---------------------------------------------------------------------------
__global__ __launch_bounds__(256, 4) void proj_v_kernel(
    const float* __restrict__ f, const unsigned short* __restrict__ WvB,
    const float* __restrict__ bv, unsigned short* __restrict__ vB)
{
    const int t    = threadIdx.x;
    const int lane = t & 63;
    const int w    = t >> 6;
    const int l31  = lane & 31;
    const int h    = lane >> 5;
    const int nb   = blockIdx.x * 32;
    const int cb   = w * 64;

    f32x16 acc[2];
#pragma unroll
    for (int cf = 0; cf < 2; ++cf)
#pragma unroll
        for (int r = 0; r < 16; ++r) acc[cf][r] = 0.f;

    const float* frow = f + (size_t)(nb + l31) * CC;
#pragma unroll
    for (int ks = 0; ks < 16; ++ks) {
        const int k0 = ks * 16 + 8 * h;
        float4 a0 = *(const float4*)(frow + k0);
        float4 a1 = *(const float4*)(frow + k0 + 4);
        bf16x8 af;
        af[0] = (short)f2bf(a0.x); af[1] = (short)f2bf(a0.y);
        af[2] = (short)f2bf(a0.z); af[3] = (short)f2bf(a0.w);
        af[4] = (short)f2bf(a1.x); af[5] = (short)f2bf(a1.y);
        af[6] = (short)f2bf(a1.z); af[7] = (short)f2bf(a1.w);
#pragma unroll
        for (int cf = 0; cf < 2; ++cf) {
            const bf16x8 bw = *(const bf16x8*)(WvB + (size_t)(cb + 32 * cf + l31) * CC + k0);
            acc[cf] = __builtin_amdgcn_mfma_f32_32x32x16_bf16(af, bw, acc[cf], 0, 0, 0);
        }
    }
#pragma unroll
    for (int cf = 0; cf < 2; ++cf) {
        const int cg = cb + 32 * cf + l31;
        const float bvc = bv[cg];
#pragma unroll
        for (int rg = 0; rg < 4; ++rg) {
            const int ib = (nb >> 3) + rg;
            s16x4 pk;
#pragma unroll
            for (int r = 0; r < 4; ++r)
                pk[r] = (short)f2bf(acc[cf][4 * rg + r] + bvc);
            *(s16x4*)(vB + ((size_t)ib * CC + cg) * 8 + 4 * h) = pk;
        }
    }
}

// ---------------------------------------------------------------------------
// Kernel 2: per-i partial denominators over a j-range (no max tracking;
// exp2-domain energies bounded, f32-safe). f16 E: 2 MFMAs per 32x32 tile.
// ---------------------------------------------------------------------------
__global__ __launch_bounds__(256, 4) void pass1_kernel(
    const unsigned short* __restrict__ qf,
    float* __restrict__ ps)
{
    const int t    = threadIdx.x;
    const int lane = t & 63;
    const int w    = t >> 6;
    const int l31  = lane & 31;
    const int h    = lane >> 5;
    const int i0   = (blockIdx.x & 255) * 32;
    const int js   = blockIdx.x >> 8;
    const int JCH  = NN / JS / 4;            // 512 j per wave
    const int jbase = js * (NN / JS) + w * JCH;

    const size_t qir = (size_t)(i0 + l31) * CQK;
    const f16x8 bi0 = *(const f16x8*)(qf + qir + 8 * h);
    const f16x8 bi1 = *(const f16x8*)(qf + qir + 16 + 8 * h);

    float s = 0.f;

#pragma unroll 2
    for (int st = 0; st < JCH; st += 32) {
        const size_t qjr = (size_t)(jbase + st + l31) * CQK;
        const f16x8 aj0 = *(const f16x8*)(qf + qjr + 8 * h);
        const f16x8 aj1 = *(const f16x8*)(qf + qjr + 16 + 8 * h);
        f32x16 ee = {0,0,0,0,0,0,0,0,0,0,0,0,0,0,0,0};
        ee = __builtin_amdgcn_mfma_f32_32x32x16_f16(aj0, bi0, ee, 0, 0, 0);
        ee = __builtin_amdgcn_mfma_f32_32x32x16_f16(aj1, bi1, ee, 0, 0, 0);
        float a_ = 0.f;
#pragma unroll
        for (int r = 0; r < 16; ++r) a_ += fexp2(ee[r]);
        s += a_;
    }
    s += __shfl_xor(s, 32);      // merge the two h-halves (same i-col)

    __shared__ float rs[4][32];
    if (lane < 32) rs[w][l31] = s;
    __syncthreads();
    if (t < 32) {
        float sf = rs[0][t] + rs[1][t] + rs[2][t] + rs[3][t];
        ps[(size_t)js * NN + i0 + t] = sf;
    }
}

// ---------------------------------------------------------------------------
// Kernel 2b: merge j-split partial sums; bias[i] = log2(sum).
// ---------------------------------------------------------------------------
__global__ __launch_bounds__(256) void finalize_kernel(
    const float* __restrict__ ps, float* __restrict__ bias)
{
    int i = blockIdx.x * 256 + threadIdx.x;
    float s = ps[i];
#pragma unroll
    for (int k = 1; k < JS; ++k) s += ps[(size_t)k * NN + i];
    bias[i] = __builtin_amdgcn_logf(s);   // v_log_f32 = log2
}

// ---------------------------------------------------------------------------
// Kernel 3: barrier-free PV (r11 structure, simplified loop; r7/r9 showed
// manual pipelining is compiler-redundant). f16 E (2-MFMA chain), bf16 PV.
// grid 512 x 256 thr (4 waves). Block: 64 j x 256 c. Wave: 32j x 128c.
// P redistribution: round-3-verified shfl_xor(32)+select.
// __launch_bounds__(256,2): no register cap (r6 lesson).
// ---------------------------------------------------------------------------
template<int ISPLIT, bool DIRECT>
__global__ __launch_bounds__(256, 2) void pass2_kernel(
    const unsigned short* __restrict__ qf,
    const unsigned short* __restrict__ vB,
    const float* __restrict__ bias,
    const float* __restrict__ f,
    const float* __restrict__ gp,
    float* __restrict__ dst)
{
    const int t    = threadIdx.x;
    const int lane = t & 63;
    const int w    = t >> 6;
    const int l31  = lane & 31;
    const int h    = lane >> 5;

    int jblk, isp;
    if (ISPLIT == 4) {
        // XCD-aware: each XCD pair owns one isp -> its vB/q slices stay in L2
        const int bid = blockIdx.x;
        isp  = (bid & 7) >> 1;
        jblk = ((bid >> 3) << 1) | (bid & 1);   // 0..127, bijective
    } else if (ISPLIT == 2) {
        isp  = blockIdx.x & 1;
        jblk = blockIdx.x >> 1;
    } else {
        isp  = 0;
        jblk = blockIdx.x;
    }
    const int jb   = jblk * 64;
    const int jrow = jb + 32 * (w & 1);
    const int cb   = 128 * (w >> 1);
    const int IL   = NN / ISPLIT;
    const int ibase = isp * IL;
    const int iend  = ibase + IL;

    const size_t qjr = (size_t)(jrow + l31) * CQK;
    const f16x8 bj0 = *(const f16x8*)(qf + qjr + 8 * h);
    const f16x8 bj1 = *(const f16x8*)(qf + qjr + 16 + 8 * h);

    f32x16 acc[4];
#pragma unroll
    for (int cf = 0; cf < 4; ++cf)
#pragma unroll
        for (int r = 0; r < 16; ++r) acc[cf][r] = 0.f;

#pragma unroll 1
    for (int i0s = ibase; i0s < iend; i0s += 32) {
        // q_i A-frags (f16)
        const size_t qir = (size_t)(i0s + l31) * CQK;
        const f16x8 ai0 = *(const f16x8*)(qf + qir + 8 * h);
        const f16x8 ai1 = *(const f16x8*)(qf + qir + 16 + 8 * h);

        // bias for rows i = i0s + 4h + r + 8rg
        const f32x4 b40 = *(const f32x4*)(bias + i0s + 0  + 4 * h);
        const f32x4 b41 = *(const f32x4*)(bias + i0s + 8  + 4 * h);
        const f32x4 b42 = *(const f32x4*)(bias + i0s + 16 + 4 * h);
        const f32x4 b43 = *(const f32x4*)(bias + i0s + 24 + 4 * h);

        // E tile: 2-MFMA f16 chain, D[row=i][col=j]
        f32x16 ee = {0,0,0,0,0,0,0,0,0,0,0,0,0,0,0,0};
        ee = __builtin_amdgcn_mfma_f32_32x32x16_f16(ai0, bj0, ee, 0, 0, 0);
        ee = __builtin_amdgcn_mfma_f32_32x32x16_f16(ai1, bj1, ee, 0, 0, 0);

        // p = exp2(e - bias_i), truncation-packed i-pairs
        int d0[4], d1[4];
        d0[0] = packbf(fexp2(ee[0]  - b40[0]), fexp2(ee[1]  - b40[1]));
        d1[0] = packbf(fexp2(ee[2]  - b40[2]), fexp2(ee[3]  - b40[3]));
        d0[1] = packbf(fexp2(ee[4]  - b41[0]), fexp2(ee[5]  - b41[1]));
        d1[1] = packbf(fexp2(ee[6]  - b41[2]), fexp2(ee[7]  - b41[3]));
        d0[2] = packbf(fexp2(ee[8]  - b42[0]), fexp2(ee[9]  - b42[1]));
        d1[2] = packbf(fexp2(ee[10] - b42[2]), fexp2(ee[11] - b42[3]));
        d0[3] = packbf(fexp2(ee[12] - b43[0]), fexp2(ee[13] - b43[1]));
        d1[3] = packbf(fexp2(ee[14] - b43[2]), fexp2(ee[15] - b43[3]));

        // redistribute (verified shfl_xor(32)+select) and PV (bf16)
#pragma unroll
        for (int s2 = 0; s2 < 2; ++s2) {
            const int a_ = d0[2 * s2], b_ = d0[2 * s2 + 1];
            const int c_ = d1[2 * s2], d_ = d1[2 * s2 + 1];
            const int pa = __shfl_xor(a_, 32);
            const int pb = __shfl_xor(b_, 32);
            const int pc = __shfl_xor(c_, 32);
            const int pd = __shfl_xor(d_, 32);
            union { int i[4]; bf16x8 v; } pf;
            pf.i[0] = h ? pb : a_;
            pf.i[1] = h ? pd : c_;
            pf.i[2] = h ? b_ : pa;
            pf.i[3] = h ? d_ : pc;
            const size_t vbase = ((size_t)((i0s >> 3) + 2 * s2 + h) * CC + cb + l31) * 8;
#pragma unroll
            for (int cf = 0; cf < 4; ++cf) {
                const bf16x8 vf = *(const bf16x8*)(vB + vbase + (size_t)cf * 256);
                acc[cf] = __builtin_amdgcn_mfma_f32_32x32x16_bf16(pf.v, vf, acc[cf], 0, 0, 0);
            }
        }
    }

    if (DIRECT) {
        const float g = gp[0];
#pragma unroll
        for (int cf = 0; cf < 4; ++cf) {
            const int c = cb + 32 * cf + l31;
#pragma unroll
            for (int rg = 0; rg < 4; ++rg)
#pragma unroll
                for (int r = 0; r < 4; ++r) {
                    const int j = jrow + 4 * h + r + 8 * rg;
                    dst[(size_t)j * CC + c] =
                        fmaf(g, acc[cf][4 * rg + r], f[(size_t)j * CC + c]);
                }
        }
    } else {
        float* part = dst + (size_t)isp * NN * CC;
#pragma unroll
        for (int cf = 0; cf < 4; ++cf) {
            const int c = cb + 32 * cf + l31;
#pragma unroll
            for (int rg = 0; rg < 4; ++rg)
#pragma unroll
                for (int r = 0; r < 4; ++r) {
                    const int j = jrow + 4 * h + r + 8 * rg;
                    part[(size_t)j * CC + c] = acc[cf][4 * rg + r];
                }
        }
    }
}

// ---------------------------------------------------------------------------
// Kernel 4: out = gamma * sum_splits(part) + f
// ---------------------------------------------------------------------------
template<int SPLIT>
__global__ __launch_bounds__(256) void reduce_kernel(
    const float* __restrict__ part, const float* __restrict__ f,
    const float* __restrict__ gp, float* __restrict__ out)
{
    size_t idx = (size_t)blockIdx.x * 256 + threadIdx.x;   // f32x4 units
    const f32x4* p4 = (const f32x4*)part;
    f32x4 s = p4[idx];
#pragma unroll
    for (int k = 1; k < SPLIT; ++k) s += p4[(size_t)k * (NN * CC / 4) + idx];
    f32x4 fv = ((const f32x4*)f)[idx];
    float g = gp[0];
    f32x4 o;
#pragma unroll
    for (int r = 0; r < 4; ++r) o[r] = fmaf(g, s[r], fv[r]);
    ((f32x4*)out)[idx] = o;
}

// ---------------------------------------------------------------------------
extern "C" void kernel_launch(void* const* d_in, const int* in_sizes, int n_in,
                              void* d_out, int out_size, void* d_ws, size_t ws_size,
                              hipStream_t stream) {
    const float* f     = (const float*)d_in[0];
    const float* Wqk   = (const float*)d_in[1];
    const float* Wv    = (const float*)d_in[2];
    const float* bv    = (const float*)d_in[3];
    const float* gamma = (const float*)d_in[4];
    float* out = (float*)d_out;

    char* ws = (char*)d_ws;
    unsigned short* qf  = (unsigned short*)ws;                         // 512 KB
    unsigned short* vB  = (unsigned short*)(ws + (1 << 20));           // 4 MB
    float* ps   = (float*)(ws + (5 << 20));                            // 128 KB
    float* bias = (float*)(ws + (5 << 20) + (256 << 10));              // 32 KB
    unsigned short* WvB = (unsigned short*)(ws + (5 << 20) + (512 << 10)); // 128 KB
    float* part = (float*)(ws + (6 << 20));                            // ISPLIT*8 MB

    conv_w_kernel<<<dim3(CC * CC / 1024), dim3(256), 0, stream>>>(Wv, WvB);
    proj_q_kernel<<<dim3(NN / 8), dim3(256), 0, stream>>>(f, Wqk, qf);
    proj_v_kernel<<<dim3(NN / 32), dim3(256), 0, stream>>>(f, WvB, bv, vB);
    pass1_kernel<<<dim3((NN / 32) * JS), dim3(256), 0, stream>>>(qf, ps);
    finalize_kernel<<<dim3(NN / 256), dim3(256), 0, stream>>>(ps, bias);

    const size_t PB = (size_t)NN * CC * 4;   // one partial buffer: 8 MB
    const size_t B0 = (size_t)6 << 20;
    if (ws_size >= B0 + 4 * PB) {
        pass2_kernel<4, false><<<dim3(128 * 4), dim3(256), 0, stream>>>(qf, vB, bias, f, gamma, part);
        reduce_kernel<4><<<dim3(NN * CC / 1024), dim3(256), 0, stream>>>(part, f, gamma, out);
    } else if (ws_size >= B0 + 2 * PB) {
        pass2_kernel<2, false><<<dim3(128 * 2), dim3(256), 0, stream>>>(qf, vB, bias, f, gamma, part);
        reduce_kernel<2><<<dim3(NN * CC / 1024), dim3(256), 0, stream>>>(part, f, gamma, out);
    } else if (ws_size >= B0 + 1 * PB) {
        pass2_kernel<1, false><<<dim3(128), dim3(256), 0, stream>>>(qf, vB, bias, f, gamma, part);
        reduce_kernel<1><<<dim3(NN * CC / 1024), dim3(256), 0, stream>>>(part, f, gamma, out);
    } else {
        pass2_kernel<1, true><<<dim3(128), dim3(256), 0, stream>>>(qf, vB, bias, f, gamma, out);
    }
}

// Round 15
// 139.836 us; speedup vs baseline: 1.4334x; 1.1680x over previous
//
#include <hip/hip_runtime.h>
#include <hip/hip_bf16.h>

#define NN 8192
#define CC 256
#define CQK 32
#define JS 4   // pass1 j-splits

using bf16x8 = __attribute__((ext_vector_type(8))) short;
using f16x8  = __attribute__((ext_vector_type(8))) _Float16;
using s16x4  = __attribute__((ext_vector_type(4))) short;
using f32x4  = __attribute__((ext_vector_type(4))) float;
using f32x16 = __attribute__((ext_vector_type(16))) float;

static __device__ __forceinline__ unsigned short f2bf(float x) {
    union { __hip_bfloat16 h; unsigned short u; } cv;
    cv.h = __float2bfloat16(x);
    return cv.u;
}
static __device__ __forceinline__ float fexp2(float x) { return __builtin_amdgcn_exp2f(x); }
// pack two positive f32 -> packed bf16 dword by TRUNCATION (p > 0 always).
static __device__ __forceinline__ int packbf(float lo, float hi) {
    union { float f; unsigned u; } a, b;
    a.f = lo; b.f = hi;
    return (int)((b.u & 0xFFFF0000u) | (a.u >> 16));
}

// ---------------------------------------------------------------------------
// Kernel 0: Wv f32 -> bf16 once.
// ---------------------------------------------------------------------------
__global__ __launch_bounds__(256) void conv_w_kernel(
    const float* __restrict__ Wv, unsigned short* __restrict__ WvB)
{
    const int idx = (blockIdx.x * 256 + threadIdx.x) * 4;   // 64 blocks
    float4 v = *(const float4*)(Wv + idx);
    s16x4 pk;
    pk[0] = (short)f2bf(v.x); pk[1] = (short)f2bf(v.y);
    pk[2] = (short)f2bf(v.z); pk[3] = (short)f2bf(v.w);
    *(s16x4*)(WvB + idx) = pk;
}

// ---------------------------------------------------------------------------
// Kernel 1a: q = (f @ Wqk^T) * sqrt(log2 e), stored as single f16
// (validated r14: absmax unchanged vs bf16 hi/lo).
// ---------------------------------------------------------------------------
__global__ __launch_bounds__(256) void proj_q_kernel(
    const float* __restrict__ f, const float* __restrict__ Wqk,
    unsigned short* __restrict__ qf)
{
    __shared__ __align__(16) float fl[8][CC];
    const int t  = threadIdx.x;
    const int r0 = blockIdx.x * 8;
    {
        const float4* src = (const float4*)(f + (size_t)r0 * CC);
        float4* dst = (float4*)&fl[0][0];
        dst[t]       = src[t];
        dst[t + 256] = src[t + 256];
    }
    __syncthreads();
    const int cq = t & 31;
    const int rg = t >> 5;
    const float4* w4 = (const float4*)(Wqk + (size_t)cq * CC);
    float a = 0.f;
    for (int k4 = 0; k4 < 64; ++k4) {
        float4 wq = w4[k4];
        const float4 fv = *(const float4*)&fl[rg][k4 * 4];
        a = fmaf(wq.x, fv.x, a);
        a = fmaf(wq.y, fv.y, a);
        a = fmaf(wq.z, fv.z, a);
        a = fmaf(wq.w, fv.w, a);
    }
    a *= 1.2011224087864498f;              // sqrt(log2 e) -> exp2 domain
    union { _Float16 h; unsigned short u; } cv;
    cv.h = (_Float16)a;                    // RNE
    qf[(size_t)(r0 + rg) * CQK + cq] = cv.u;
}

// ---------------------------------------------------------------------------
// Kernel 1b: v = f @ Wv^T + bv via bf16 32x32x16 MFMA; Wv pre-converted bf16.
// Output layout vB[i>>3][c][i&7] bf16 -> PV B-frags are coalesced b128 loads.
// ---------------------------------------------------------------------------
__global__ __launch_bounds__(256, 4) void proj_v_kernel(
    const float* __restrict__ f, const unsigned short* __restrict__ WvB,
    const float* __restrict__ bv, unsigned short* __restrict__ vB)
{
    const int t    = threadIdx.x;
    const int lane = t & 63;
    const int w    = t >> 6;
    const int l31  = lane & 31;
    const int h    = lane >> 5;
    const int nb   = blockIdx.x * 32;
    const int cb   = w * 64;

    f32x16 acc[2];
#pragma unroll
    for (int cf = 0; cf < 2; ++cf)
#pragma unroll
        for (int r = 0; r < 16; ++r) acc[cf][r] = 0.f;

    const float* frow = f + (size_t)(nb + l31) * CC;
#pragma unroll
    for (int ks = 0; ks < 16; ++ks) {
        const int k0 = ks * 16 + 8 * h;
        float4 a0 = *(const float4*)(frow + k0);
        float4 a1 = *(const float4*)(frow + k0 + 4);
        bf16x8 af;
        af[0] = (short)f2bf(a0.x); af[1] = (short)f2bf(a0.y);
        af[2] = (short)f2bf(a0.z); af[3] = (short)f2bf(a0.w);
        af[4] = (short)f2bf(a1.x); af[5] = (short)f2bf(a1.y);
        af[6] = (short)f2bf(a1.z); af[7] = (short)f2bf(a1.w);
#pragma unroll
        for (int cf = 0; cf < 2; ++cf) {
            const bf16x8 bw = *(const bf16x8*)(WvB + (size_t)(cb + 32 * cf + l31) * CC + k0);
            acc[cf] = __builtin_amdgcn_mfma_f32_32x32x16_bf16(af, bw, acc[cf], 0, 0, 0);
        }
    }
#pragma unroll
    for (int cf = 0; cf < 2; ++cf) {
        const int cg = cb + 32 * cf + l31;
        const float bvc = bv[cg];
#pragma unroll
        for (int rg = 0; rg < 4; ++rg) {
            const int ib = (nb >> 3) + rg;
            s16x4 pk;
#pragma unroll
            for (int r = 0; r < 4; ++r)
                pk[r] = (short)f2bf(acc[cf][4 * rg + r] + bvc);
            *(s16x4*)(vB + ((size_t)ib * CC + cg) * 8 + 4 * h) = pk;
        }
    }
}

// ---------------------------------------------------------------------------
// Kernel 2: per-i partial denominators (no max tracking; exp2-domain bounded).
// f16 E: 2 MFMAs per 32x32 tile.
// ---------------------------------------------------------------------------
__global__ __launch_bounds__(256, 4) void pass1_kernel(
    const unsigned short* __restrict__ qf,
    float* __restrict__ ps)
{
    const int t    = threadIdx.x;
    const int lane = t & 63;
    const int w    = t >> 6;
    const int l31  = lane & 31;
    const int h    = lane >> 5;
    const int i0   = (blockIdx.x & 255) * 32;
    const int js   = blockIdx.x >> 8;
    const int JCH  = NN / JS / 4;            // 512 j per wave
    const int jbase = js * (NN / JS) + w * JCH;

    const size_t qir = (size_t)(i0 + l31) * CQK;
    const f16x8 bi0 = *(const f16x8*)(qf + qir + 8 * h);
    const f16x8 bi1 = *(const f16x8*)(qf + qir + 16 + 8 * h);

    float s = 0.f;

#pragma unroll 2
    for (int st = 0; st < JCH; st += 32) {
        const size_t qjr = (size_t)(jbase + st + l31) * CQK;
        const f16x8 aj0 = *(const f16x8*)(qf + qjr + 8 * h);
        const f16x8 aj1 = *(const f16x8*)(qf + qjr + 16 + 8 * h);
        f32x16 ee = {0,0,0,0,0,0,0,0,0,0,0,0,0,0,0,0};
        ee = __builtin_amdgcn_mfma_f32_32x32x16_f16(aj0, bi0, ee, 0, 0, 0);
        ee = __builtin_amdgcn_mfma_f32_32x32x16_f16(aj1, bi1, ee, 0, 0, 0);
        float a_ = 0.f;
#pragma unroll
        for (int r = 0; r < 16; ++r) a_ += fexp2(ee[r]);
        s += a_;
    }
    s += __shfl_xor(s, 32);      // merge the two h-halves (same i-col)

    __shared__ float rs[4][32];
    if (lane < 32) rs[w][l31] = s;
    __syncthreads();
    if (t < 32) {
        float sf = rs[0][t] + rs[1][t] + rs[2][t] + rs[3][t];
        ps[(size_t)js * NN + i0 + t] = sf;
    }
}

// ---------------------------------------------------------------------------
// Kernel 2b: merge j-split partial sums; bias[i] = log2(sum).
// ---------------------------------------------------------------------------
__global__ __launch_bounds__(256) void finalize_kernel(
    const float* __restrict__ ps, float* __restrict__ bias)
{
    int i = blockIdx.x * 256 + threadIdx.x;
    float s = ps[i];
#pragma unroll
    for (int k = 1; k < JS; ++k) s += ps[(size_t)k * NN + i];
    bias[i] = __builtin_amdgcn_logf(s);   // v_log_f32 = log2
}

// ---------------------------------------------------------------------------
// Kernel 3: barrier-free PV = r11's prefetched double-buffered macro-step
// structure + r14's f16 E. r14 lesson: without the cross-step prefetch
// (unroll-1 body) loads are exposed and wall pins at ~96 us regardless of
// issued work; r11's structure hides them.
// grid 512 x 256 thr (4 waves). Block: 64 j x 256 c. Wave: 32j x 128c.
// __launch_bounds__(256,2): no register cap (r6 lesson).
// ---------------------------------------------------------------------------
#define LOADQF(A0, A1, NI)                                                     \
    {                                                                          \
        const size_t qnr = (size_t)((NI) + l31) * CQK;                         \
        A0 = *(const f16x8*)(qf + qnr + 8 * h);                                \
        A1 = *(const f16x8*)(qf + qnr + 16 + 8 * h);                           \
    }

#define LOADVF2(VF, I)                                                         \
    _Pragma("unroll")                                                          \
    for (int s2 = 0; s2 < 2; ++s2)                                             \
        _Pragma("unroll")                                                      \
        for (int cf = 0; cf < 4; ++cf)                                         \
            VF[s2][cf] = *(const bf16x8*)(                                     \
                vB + ((size_t)(((I) >> 3) + 2 * s2 + h) * CC + cb + 32 * cf + l31) * 8);

#define LOADB42(B4, I)                                                         \
    _Pragma("unroll")                                                          \
    for (int rg = 0; rg < 4; ++rg)                                             \
        B4[rg] = *(const f32x4*)(bias + (I) + 8 * rg + 4 * h);

#define ECOMPF(EE, A0, A1)                                                     \
    {                                                                          \
        f32x16 z_ = {0,0,0,0,0,0,0,0,0,0,0,0,0,0,0,0};                         \
        z_ = __builtin_amdgcn_mfma_f32_32x32x16_f16(A1, bj1, z_, 0, 0, 0);     \
        EE = __builtin_amdgcn_mfma_f32_32x32x16_f16(A0, bj0, z_, 0, 0, 0);     \
    }

#define FINISH2(EE, B4, VF)                                                    \
    {                                                                          \
        int d0[4], d1[4];                                                      \
        _Pragma("unroll")                                                      \
        for (int rg = 0; rg < 4; ++rg) {                                       \
            float p0 = fexp2(EE[4 * rg + 0] - B4[rg][0]);                      \
            float p1 = fexp2(EE[4 * rg + 1] - B4[rg][1]);                      \
            float p2 = fexp2(EE[4 * rg + 2] - B4[rg][2]);                      \
            float p3 = fexp2(EE[4 * rg + 3] - B4[rg][3]);                      \
            d0[rg] = packbf(p0, p1);                                           \
            d1[rg] = packbf(p2, p3);                                           \
        }                                                                      \
        _Pragma("unroll")                                                      \
        for (int s2 = 0; s2 < 2; ++s2) {                                       \
            const int a_ = d0[2 * s2], b_ = d0[2 * s2 + 1];                    \
            const int c_ = d1[2 * s2], d_ = d1[2 * s2 + 1];                    \
            const int pa = __shfl_xor(a_, 32);                                 \
            const int pb = __shfl_xor(b_, 32);                                 \
            const int pc = __shfl_xor(c_, 32);                                 \
            const int pd = __shfl_xor(d_, 32);                                 \
            union { int i[4]; bf16x8 v; } pf;                                  \
            pf.i[0] = h ? pb : a_;                                             \
            pf.i[1] = h ? pd : c_;                                             \
            pf.i[2] = h ? b_ : pa;                                             \
            pf.i[3] = h ? d_ : pc;                                             \
            _Pragma("unroll")                                                  \
            for (int cf = 0; cf < 4; ++cf)                                     \
                acc[cf] = __builtin_amdgcn_mfma_f32_32x32x16_bf16(             \
                    pf.v, VF[s2][cf], acc[cf], 0, 0, 0);                       \
        }                                                                      \
    }

template<int ISPLIT, bool DIRECT>
__global__ __launch_bounds__(256, 2) void pass2_kernel(
    const unsigned short* __restrict__ qf,
    const unsigned short* __restrict__ vB,
    const float* __restrict__ bias,
    const float* __restrict__ f,
    const float* __restrict__ gp,
    float* __restrict__ dst)
{
    const int t    = threadIdx.x;
    const int lane = t & 63;
    const int w    = t >> 6;
    const int l31  = lane & 31;
    const int h    = lane >> 5;

    int jblk, isp;
    if (ISPLIT == 4) {
        // XCD-aware: each XCD pair owns one isp -> its vB/q slices stay in L2
        const int bid = blockIdx.x;
        isp  = (bid & 7) >> 1;
        jblk = ((bid >> 3) << 1) | (bid & 1);   // 0..127, bijective
    } else if (ISPLIT == 2) {
        isp  = blockIdx.x & 1;
        jblk = blockIdx.x >> 1;
    } else {
        isp  = 0;
        jblk = blockIdx.x;
    }
    const int jb   = jblk * 64;
    const int jrow = jb + 32 * (w & 1);
    const int cb   = 128 * (w >> 1);
    const int IL   = NN / ISPLIT;
    const int ibase = isp * IL;
    const int iend  = ibase + IL;

    const size_t qjr = (size_t)(jrow + l31) * CQK;
    const f16x8 bj0 = *(const f16x8*)(qf + qjr + 8 * h);
    const f16x8 bj1 = *(const f16x8*)(qf + qjr + 16 + 8 * h);

    f32x16 acc[4];
#pragma unroll
    for (int cf = 0; cf < 4; ++cf)
#pragma unroll
        for (int r = 0; r < 16; ++r) acc[cf][r] = 0.f;

    f32x16 eeA, eeB;
    f32x4  b4A[4], b4B[4];
    f16x8  qa0, qa1, qb0, qb1;
    bf16x8 vfA[2][4], vfB[2][4];

    // prologue: E(step0) ready in eeA; qb/b4B staged for step1; vfA for step0
    LOADQF(qa0, qa1, ibase)
    LOADB42(b4A, ibase)
    LOADVF2(vfA, ibase)
    ECOMPF(eeA, qa0, qa1)
    LOADQF(qb0, qb1, ibase + 32)
    LOADB42(b4B, ibase + 32)

    for (int i0s = ibase; i0s < iend; i0s += 64) {
        const int n1 = (i0s + 64 < iend) ? i0s + 64 : ibase;   // clamp: extra
        const int n2 = (i0s + 96 < iend) ? i0s + 96 : ibase;   // work discarded
        // stage A: E(i0s+32) + vf(i0s+32) in flight over FINISH(i0s)
        LOADVF2(vfB, i0s + 32)
        ECOMPF(eeB, qb0, qb1)
        LOADQF(qa0, qa1, n1)
        FINISH2(eeA, b4A, vfA)
        LOADB42(b4A, n1)
        // stage B: E(i0s+64) + vf(i0s+64) in flight over FINISH(i0s+32)
        LOADVF2(vfA, n1)
        ECOMPF(eeA, qa0, qa1)
        LOADQF(qb0, qb1, n2)
        FINISH2(eeB, b4B, vfB)
        LOADB42(b4B, n2)
    }

    if (DIRECT) {
        const float g = gp[0];
#pragma unroll
        for (int cf = 0; cf < 4; ++cf) {
            const int c = cb + 32 * cf + l31;
#pragma unroll
            for (int rg = 0; rg < 4; ++rg)
#pragma unroll
                for (int r = 0; r < 4; ++r) {
                    const int j = jrow + 4 * h + r + 8 * rg;
                    dst[(size_t)j * CC + c] =
                        fmaf(g, acc[cf][4 * rg + r], f[(size_t)j * CC + c]);
                }
        }
    } else {
        float* part = dst + (size_t)isp * NN * CC;
#pragma unroll
        for (int cf = 0; cf < 4; ++cf) {
            const int c = cb + 32 * cf + l31;
#pragma unroll
            for (int rg = 0; rg < 4; ++rg)
#pragma unroll
                for (int r = 0; r < 4; ++r) {
                    const int j = jrow + 4 * h + r + 8 * rg;
                    part[(size_t)j * CC + c] = acc[cf][4 * rg + r];
                }
        }
    }
}

// ---------------------------------------------------------------------------
// Kernel 4: out = gamma * sum_splits(part) + f
// ---------------------------------------------------------------------------
template<int SPLIT>
__global__ __launch_bounds__(256) void reduce_kernel(
    const float* __restrict__ part, const float* __restrict__ f,
    const float* __restrict__ gp, float* __restrict__ out)
{
    size_t idx = (size_t)blockIdx.x * 256 + threadIdx.x;   // f32x4 units
    const f32x4* p4 = (const f32x4*)part;
    f32x4 s = p4[idx];
#pragma unroll
    for (int k = 1; k < SPLIT; ++k) s += p4[(size_t)k * (NN * CC / 4) + idx];
    f32x4 fv = ((const f32x4*)f)[idx];
    float g = gp[0];
    f32x4 o;
#pragma unroll
    for (int r = 0; r < 4; ++r) o[r] = fmaf(g, s[r], fv[r]);
    ((f32x4*)out)[idx] = o;
}

// ---------------------------------------------------------------------------
extern "C" void kernel_launch(void* const* d_in, const int* in_sizes, int n_in,
                              void* d_out, int out_size, void* d_ws, size_t ws_size,
                              hipStream_t stream) {
    const float* f     = (const float*)d_in[0];
    const float* Wqk   = (const float*)d_in[1];
    const float* Wv    = (const float*)d_in[2];
    const float* bv    = (const float*)d_in[3];
    const float* gamma = (const float*)d_in[4];
    float* out = (float*)d_out;

    char* ws = (char*)d_ws;
    unsigned short* qf  = (unsigned short*)ws;                         // 512 KB
    unsigned short* vB  = (unsigned short*)(ws + (1 << 20));           // 4 MB
    float* ps   = (float*)(ws + (5 << 20));                            // 128 KB
    float* bias = (float*)(ws + (5 << 20) + (256 << 10));              // 32 KB
    unsigned short* WvB = (unsigned short*)(ws + (5 << 20) + (512 << 10)); // 128 KB
    float* part = (float*)(ws + (6 << 20));                            // ISPLIT*8 MB

    conv_w_kernel<<<dim3(CC * CC / 1024), dim3(256), 0, stream>>>(Wv, WvB);
    proj_q_kernel<<<dim3(NN / 8), dim3(256), 0, stream>>>(f, Wqk, qf);
    proj_v_kernel<<<dim3(NN / 32), dim3(256), 0, stream>>>(f, WvB, bv, vB);
    pass1_kernel<<<dim3((NN / 32) * JS), dim3(256), 0, stream>>>(qf, ps);
    finalize_kernel<<<dim3(NN / 256), dim3(256), 0, stream>>>(ps, bias);

    const size_t PB = (size_t)NN * CC * 4;   // one partial buffer: 8 MB
    const size_t B0 = (size_t)6 << 20;
    if (ws_size >= B0 + 4 * PB) {
        pass2_kernel<4, false><<<dim3(128 * 4), dim3(256), 0, stream>>>(qf, vB, bias, f, gamma, part);
        reduce_kernel<4><<<dim3(NN * CC / 1024), dim3(256), 0, stream>>>(part, f, gamma, out);
    } else if (ws_size >= B0 + 2 * PB) {
        pass2_kernel<2, false><<<dim3(128 * 2), dim3(256), 0, stream>>>(qf, vB, bias, f, gamma, part);
        reduce_kernel<2><<<dim3(NN * CC / 1024), dim3(256), 0, stream>>>(part, f, gamma, out);
    } else if (ws_size >= B0 + 1 * PB) {
        pass2_kernel<1, false><<<dim3(128), dim3(256), 0, stream>>>(qf, vB, bias, f, gamma, part);
        reduce_kernel<1><<<dim3(NN * CC / 1024), dim3(256), 0, stream>>>(part, f, gamma, out);
    } else {
        pass2_kernel<1, true><<<dim3(128), dim3(256), 0, stream>>>(qf, vB, bias, f, gamma, out);
    }
}